// Round 1
// baseline (49.040 us; speedup 1.0000x reference)
//
#include <hip/hip_runtime.h>

#define NROWS 8192
#define NCOLS 2048
#define ROWS_PER_BLOCK 64
#define BLOCK 256

// Kernel 1: partial column sums of (fx - ft), accumulated into ws via atomics.
// Each thread owns 4 consecutive columns (one float4 per array per row).
__global__ void __launch_bounds__(BLOCK)
colsum_kernel(const float* __restrict__ fx, const float* __restrict__ ft,
              float* __restrict__ colsum) {
    const int col4 = blockIdx.x * BLOCK + threadIdx.x;      // float4 column index
    const int row0 = blockIdx.y * ROWS_PER_BLOCK;
    const int stride4 = NCOLS / 4;                          // 512

    const float4* fx4 = reinterpret_cast<const float4*>(fx);
    const float4* ft4 = reinterpret_cast<const float4*>(ft);

    float4 acc = make_float4(0.f, 0.f, 0.f, 0.f);
    #pragma unroll 8
    for (int r = 0; r < ROWS_PER_BLOCK; ++r) {
        const int idx = (row0 + r) * stride4 + col4;
        float4 a = fx4[idx];
        float4 b = ft4[idx];
        acc.x += a.x - b.x;
        acc.y += a.y - b.y;
        acc.z += a.z - b.z;
        acc.w += a.w - b.w;
    }
    const int c = col4 * 4;
    atomicAdd(&colsum[c + 0], acc.x);
    atomicAdd(&colsum[c + 1], acc.y);
    atomicAdd(&colsum[c + 2], acc.z);
    atomicAdd(&colsum[c + 3], acc.w);
}

// Kernel 2: out = sum_k colsum[k]^2 / N^2  (single block)
__global__ void __launch_bounds__(BLOCK)
finalize_kernel(const float* __restrict__ colsum, float* __restrict__ out) {
    __shared__ float red[BLOCK / 64];
    const int tid = threadIdx.x;

    float s = 0.f;
    for (int k = tid; k < NCOLS; k += BLOCK) {
        const float v = colsum[k];
        s += v * v;
    }
    // 64-lane wave reduction
    #pragma unroll
    for (int off = 32; off > 0; off >>= 1)
        s += __shfl_down(s, off, 64);
    if ((tid & 63) == 0) red[tid >> 6] = s;
    __syncthreads();
    if (tid == 0) {
        float tot = 0.f;
        #pragma unroll
        for (int w = 0; w < BLOCK / 64; ++w) tot += red[w];
        const double inv_n2 = 1.0 / ((double)NROWS * (double)NROWS);
        out[0] = (float)((double)tot * inv_n2);
    }
}

extern "C" void kernel_launch(void* const* d_in, const int* in_sizes, int n_in,
                              void* d_out, int out_size, void* d_ws, size_t ws_size,
                              hipStream_t stream) {
    const float* fx = (const float*)d_in[0];
    const float* ft = (const float*)d_in[1];
    float* out = (float*)d_out;
    float* colsum = (float*)d_ws;   // NCOLS floats

    // ws is poisoned (0xAA) before timing and never re-poisoned — zero it
    // every call so the kernel is deterministic across graph replays.
    hipMemsetAsync(colsum, 0, NCOLS * sizeof(float), stream);

    dim3 grid1(NCOLS / 4 / BLOCK, NROWS / ROWS_PER_BLOCK);   // 2 x 128 = 256 blocks
    colsum_kernel<<<grid1, BLOCK, 0, stream>>>(fx, ft, colsum);

    finalize_kernel<<<1, BLOCK, 0, stream>>>(colsum, out);
}